// Round 9
// baseline (224.673 us; speedup 1.0000x reference)
//
#include <hip/hip_runtime.h>
#include <hip/hip_bf16.h>

// DCN v2 (modulated deformable 3x3 conv) + BN(eval) + ReLU, fused, MFMA version.
// B=4, C=64, O=64, H=W=128. fp32 in/out; bf16 MFMA (16x16x32) w/ fp32 accum.
//
// Both convs are GEMMs per 64-pixel block:
//   offset conv: [64px x 576] x [576 x 27->32]
//   main conv  : [64px x 576] x [576 x 64]   (A = deformable-sampled values)
// K layout: k = c*10 + tap (taps padded 9->10 with zeros) -> K=640, processed in
// FOUR chunks of 16 channels (K=160, 5 MFMA steps each). Round 8 used 2x32-ch
// chunks -> samp 42KB -> LDS 49664 -> 3 blocks/CU -> 19.6% occupancy, ~60% of
// cycles in waitcnt stalls. 16-ch chunks cut samp to 21.5KB (LDS ~29KB),
// raising the cap to the grid limit of 4 blocks/CU (16 waves/CU).
//
// A staged in LDS bf16 [px][KPAD=168]; row stride 336 B = 21*16 keeps
// ds_read_b128 16-B aligned. B pre-swizzled into d_ws (prep kernel) in
// fragment order: Wb[kb][nt][lane][j] = W[k=kb*32+(lane>>4)*8+j][n=nt*16+(lane&15)].
//
// MFMA layouts (m89/m120-verified): A[m=lane&15][k=(lane>>4)*8+j];
// B[k=(lane>>4)*8+j][n=lane&15]; D: n=lane&15, m=(lane>>4)*4+reg.
//
// REGISTER NOTE (R4-R7 evidence): plain __launch_bounds__(256) only; any
// min-waves arg triggers catastrophic scratch spill.

#define HH 128
#define WW 128
#define KPAD 168            // 160 + 8 pad ushorts; 336 B rows (16-B aligned)

typedef __attribute__((ext_vector_type(8))) short bf16x8;
typedef __attribute__((ext_vector_type(4))) float f32x4;

__device__ __forceinline__ unsigned short f2bf(float f) {
    union { __hip_bfloat16 b; unsigned short u; } cv;
    cv.b = __float2bfloat16(f);
    return cv.u;
}

// ws layout (ushort): WbM[20][4][64][8] = 40960 | WbO[20][2][64][8] = 20480
#define WBM_ELEMS 40960
#define WBO_ELEMS 20480

// ---------------- prep: swizzle weights into B-fragment order, bf16 ----------------
__global__ __launch_bounds__(256) void prep_kernel(
    const float* __restrict__ w_off,
    const float* __restrict__ wgt,
    unsigned short* __restrict__ ws)
{
    int t = blockIdx.x * 256 + threadIdx.x;
    if (t < WBM_ELEMS) {
        int j = t & 7, lane = (t >> 3) & 63, nt = (t >> 9) & 3, kb = t >> 11;
        int k = kb * 32 + ((lane >> 4) << 3) + j;
        int n = nt * 16 + (lane & 15);
        int c = k / 10, tp = k - c * 10;
        ws[t] = (tp < 9) ? f2bf(wgt[n * 576 + c * 9 + tp]) : (unsigned short)0;
    } else if (t < WBM_ELEMS + WBO_ELEMS) {
        int t2 = t - WBM_ELEMS;
        int j = t2 & 7, lane = (t2 >> 3) & 63, nt = (t2 >> 9) & 1, kb = t2 >> 10;
        int k = kb * 32 + ((lane >> 4) << 3) + j;
        int n = nt * 16 + (lane & 15);
        int c = k / 10, tp = k - c * 10;
        ws[t] = (tp < 9 && n < 27) ? f2bf(w_off[n * 576 + c * 9 + tp]) : (unsigned short)0;
    }
}

// ---------------- main kernel ----------------
__global__ __launch_bounds__(256) void DeformConv_14568529068723_kernel(
    const float* __restrict__ x,
    const float* __restrict__ b_off,
    const float* __restrict__ bias,
    const float* __restrict__ gamma,
    const float* __restrict__ beta,
    const float* __restrict__ rmean,
    const float* __restrict__ rvar,
    const unsigned short* __restrict__ ws,
    float* __restrict__ out)
{
    __shared__ __align__(16) unsigned short samp[64 * KPAD];  // 21504 B; reused as dT f32[64][65]
    __shared__ float offs[27 * 64];                           // [oc][px]
    __shared__ float sbuf[176];                               // 0-63 scale, 64-127 bias2, 128-154 b_off

    const int tid  = threadIdx.x;
    const int lane = tid & 63;
    const int wv   = tid >> 6;

    if (tid < 64) {
        float sc = gamma[tid] * __frsqrt_rn(rvar[tid] + 1e-5f);
        sbuf[tid] = sc;
        sbuf[64 + tid] = (bias[tid] - rmean[tid]) * sc + beta[tid];
    }
    if (tid < 27) sbuf[128 + tid] = b_off[tid];

    const int p0   = blockIdx.x * 64;
    const int b    = p0 >> 14;
    const int rem0 = p0 & 16383;
    const int h    = rem0 >> 7;
    const int w    = (rem0 & 127) + lane;      // lane = pixel
    const float* xb = x + ((size_t)b << 20);

    const bf16x8* WbM = (const bf16x8*)ws;
    const bf16x8* WbO = (const bf16x8*)(ws + WBM_ELEMS);

    __syncthreads();

    // ================= offset conv via MFMA (4 chunks of 16 channels) =================
    f32x4 accO0 = {0.f, 0.f, 0.f, 0.f};
    f32x4 accO1 = {0.f, 0.f, 0.f, 0.f};
    for (int cf = 0; cf < 4; ++cf) {
#pragma unroll
        for (int ci = 0; ci < 4; ++ci) {
            int c = cf * 16 + 4 * wv + ci;
            const float* xc = xb + (c << 14);
            float v[10];
            v[9] = 0.f;
#pragma unroll
            for (int t = 0; t < 9; ++t) {
                int yy = h + t / 3 - 1;
                int xx = w + t % 3 - 1;
                bool ok = (yy >= 0) & (yy < HH) & (xx >= 0) & (xx < WW);
                int yc = min(max(yy, 0), HH - 1);
                int xcl = min(max(xx, 0), WW - 1);
                float val = xc[yc * WW + xcl];
                v[t] = ok ? val : 0.f;
            }
            unsigned int* dst = (unsigned int*)&samp[lane * KPAD + (4 * wv + ci) * 10];
#pragma unroll
            for (int tp = 0; tp < 5; ++tp)
                dst[tp] = (unsigned int)f2bf(v[2 * tp]) | ((unsigned int)f2bf(v[2 * tp + 1]) << 16);
        }
        __syncthreads();
#pragma unroll
        for (int st = 0; st < 5; ++st) {
            bf16x8 af = *(const bf16x8*)&samp[(16 * wv + (lane & 15)) * KPAD + st * 32 + ((lane >> 4) << 3)];
            int kb = cf * 5 + st;
            bf16x8 b0 = WbO[(kb * 2 + 0) * 64 + lane];
            bf16x8 b1 = WbO[(kb * 2 + 1) * 64 + lane];
            accO0 = __builtin_amdgcn_mfma_f32_16x16x32_bf16(af, b0, accO0, 0, 0, 0);
            accO1 = __builtin_amdgcn_mfma_f32_16x16x32_bf16(af, b1, accO1, 0, 0, 0);
        }
        __syncthreads();
    }
    // D -> offs[oc][px], + bias, sigmoid masks. n=lane&15, m=(lane>>4)*4+r (+16*wv)
    {
        int n0 = lane & 15;
        int mB = 16 * wv + ((lane >> 4) << 2);
#pragma unroll
        for (int r = 0; r < 4; ++r) {
            offs[n0 * 64 + mB + r] = accO0[r] + sbuf[128 + n0];          // oc 0..15: never sigmoid
            int n1 = 16 + n0;
            if (n1 < 27) {
                float vv = accO1[r] + sbuf[128 + n1];
                if (n1 >= 18) vv = 1.0f / (1.0f + __expf(-vv));
                offs[n1 * 64 + mB + r] = vv;
            }
        }
    }
    __syncthreads();

    // ================= bilinear setup (per-lane) =================
    int   ofs4[9][4];
    float cw[9][4];
#pragma unroll
    for (int k = 0; k < 9; ++k) {
        float o1 = offs[(2 * k) * 64 + lane];
        float o2 = offs[(2 * k + 1) * 64 + lane];
        float m  = offs[(18 + k) * 64 + lane];
        float py = (float)(h + k / 3 - 1) + o1;
        float px = (float)(w + k % 3 - 1) + o2;
        float y0f = floorf(py), x0f = floorf(px);
        float dy = py - y0f, dx = px - x0f;
        int y0 = (int)y0f, x0 = (int)x0f;
        int y1 = y0 + 1, x1 = x0 + 1;
        int yc0 = min(max(y0, 0), HH - 1), yc1 = min(max(y1, 0), HH - 1);
        int xc0 = min(max(x0, 0), WW - 1), xc1 = min(max(x1, 0), WW - 1);
        float vy0 = (y0 >= 0 && y0 < HH) ? 1.0f : 0.0f;
        float vy1 = (y1 >= 0 && y1 < HH) ? 1.0f : 0.0f;
        float vx0 = (x0 >= 0 && x0 < WW) ? 1.0f : 0.0f;
        float vx1 = (x1 >= 0 && x1 < WW) ? 1.0f : 0.0f;
        ofs4[k][0] = yc0 * WW + xc0;
        ofs4[k][1] = yc0 * WW + xc1;
        ofs4[k][2] = yc1 * WW + xc0;
        ofs4[k][3] = yc1 * WW + xc1;
        cw[k][0] = (1.0f - dy) * (1.0f - dx) * m * vy0 * vx0;
        cw[k][1] = (1.0f - dy) * dx * m * vy0 * vx1;
        cw[k][2] = dy * (1.0f - dx) * m * vy1 * vx0;
        cw[k][3] = dy * dx * m * vy1 * vx1;
    }

    // ================= main conv via MFMA (4 chunks of 16 channels) =================
    f32x4 acc[4];
#pragma unroll
    for (int nt = 0; nt < 4; ++nt) acc[nt] = (f32x4){0.f, 0.f, 0.f, 0.f};

    for (int cf = 0; cf < 4; ++cf) {
#pragma unroll
        for (int ci = 0; ci < 4; ++ci) {
            int c = cf * 16 + 4 * wv + ci;
            const float* xc = xb + (c << 14);
            float sv[10];
            sv[9] = 0.f;
#pragma unroll
            for (int k = 0; k < 9; ++k) {
                sv[k] = cw[k][0] * xc[ofs4[k][0]] + cw[k][1] * xc[ofs4[k][1]]
                      + cw[k][2] * xc[ofs4[k][2]] + cw[k][3] * xc[ofs4[k][3]];
            }
            unsigned int* dst = (unsigned int*)&samp[lane * KPAD + (4 * wv + ci) * 10];
#pragma unroll
            for (int tp = 0; tp < 5; ++tp)
                dst[tp] = (unsigned int)f2bf(sv[2 * tp]) | ((unsigned int)f2bf(sv[2 * tp + 1]) << 16);
        }
        __syncthreads();
#pragma unroll
        for (int st = 0; st < 5; ++st) {
            bf16x8 af = *(const bf16x8*)&samp[(16 * wv + (lane & 15)) * KPAD + st * 32 + ((lane >> 4) << 3)];
            int kb = cf * 5 + st;
#pragma unroll
            for (int nt = 0; nt < 4; ++nt) {
                bf16x8 bf = WbM[(kb * 4 + nt) * 64 + lane];
                acc[nt] = __builtin_amdgcn_mfma_f32_16x16x32_bf16(af, bf, acc[nt], 0, 0, 0);
            }
        }
        __syncthreads();
    }

    // ================= epilogue: transpose via LDS, BN + ReLU, coalesced stores ==========
    float* dT = (float*)samp;   // [64 o][65]; 16640 B <= 21504 B
    {
        int n0 = lane & 15;
        int mB = 16 * wv + ((lane >> 4) << 2);
#pragma unroll
        for (int nt = 0; nt < 4; ++nt)
#pragma unroll
            for (int r = 0; r < 4; ++r)
                dT[(nt * 16 + n0) * 65 + mB + r] = acc[nt][r];
    }
    __syncthreads();
#pragma unroll
    for (int i = 0; i < 16; ++i) {
        int o = 16 * wv + i;
        float v = dT[o * 65 + lane];
        v = fmaxf(fmaf(v, sbuf[o], sbuf[64 + o]), 0.0f);
        out[(((size_t)(b * 64 + o)) << 14) + rem0 + lane] = v;
    }
}

extern "C" void kernel_launch(void* const* d_in, const int* in_sizes, int n_in,
                              void* d_out, int out_size, void* d_ws, size_t ws_size,
                              hipStream_t stream) {
    (void)in_sizes; (void)n_in; (void)ws_size; (void)out_size;
    const float* x     = (const float*)d_in[0];
    const float* w_off = (const float*)d_in[1];
    const float* b_off = (const float*)d_in[2];
    const float* wgt   = (const float*)d_in[3];
    const float* bias  = (const float*)d_in[4];
    const float* gamma = (const float*)d_in[5];
    const float* beta  = (const float*)d_in[6];
    const float* rmean = (const float*)d_in[7];
    const float* rvar  = (const float*)d_in[8];
    unsigned short* wsB = (unsigned short*)d_ws;
    float* outp = (float*)d_out;

    prep_kernel<<<dim3(240), dim3(256), 0, stream>>>(w_off, wgt, wsB);
    DeformConv_14568529068723_kernel<<<dim3(1024), dim3(256), 0, stream>>>(
        x, b_off, bias, gamma, beta, rmean, rvar, wsB, outp);
}

// Round 10
// 191.836 us; speedup vs baseline: 1.1712x; 1.1712x over previous
//
#include <hip/hip_runtime.h>
#include <hip/hip_bf16.h>

// DCN v2 (modulated deformable 3x3 conv) + BN(eval) + ReLU, fused, MFMA version.
// B=4, C=64, O=64, H=W=128. fp32 in/out; bf16 MFMA (16x16x32) w/ fp32 accum.
//
// R9 lesson: latency/VMEM-front-end bound (720 scattered dword gathers/lane;
// both pipes idle, occupancy insensitive). This round: bilinear corner pairs
// loaded as dwordx2 (adjacent columns) with corner-selection folded into
// per-tap weights -> phase-C gathers 576->288 per lane.
//
// GEMM mapping per 64-pixel block (K = c*10+tap, padded taps, 4 chunks of 16 ch):
//   offset conv: [64px x 576] x [576 x 27->32]
//   main conv  : [64px x 576] x [576 x 64]
// A staged in LDS bf16 [px][KPAD=168]; B pre-swizzled in d_ws by prep kernel:
// Wb[kb][nt][lane][j] = W[k=kb*32+(lane>>4)*8+j][n=nt*16+(lane&15)].
// MFMA layouts (m89/m120-verified): A[m=lane&15][k=(lane>>4)*8+j];
// B[k=(lane>>4)*8+j][n=lane&15]; D: n=lane&15, m=(lane>>4)*4+reg.
//
// REGISTER NOTE (R4-R7): plain __launch_bounds__(256) ONLY; any min-waves arg
// triggers catastrophic scratch spill.

#define HH 128
#define WW 128
#define KPAD 168            // 160 + 8 pad ushorts; 336 B rows (16-B aligned)

typedef __attribute__((ext_vector_type(8))) short bf16x8;
typedef __attribute__((ext_vector_type(4))) float f32x4;
typedef float f32x2a __attribute__((ext_vector_type(2), aligned(4)));  // 4B-aligned pair load

__device__ __forceinline__ unsigned short f2bf(float f) {
    union { __hip_bfloat16 b; unsigned short u; } cv;
    cv.b = __float2bfloat16(f);
    return cv.u;
}

// ws layout (ushort): WbM[20][4][64][8] = 40960 | WbO[20][2][64][8] = 20480
#define WBM_ELEMS 40960
#define WBO_ELEMS 20480

// ---------------- prep: swizzle weights into B-fragment order, bf16 ----------------
__global__ __launch_bounds__(256) void prep_kernel(
    const float* __restrict__ w_off,
    const float* __restrict__ wgt,
    unsigned short* __restrict__ ws)
{
    int t = blockIdx.x * 256 + threadIdx.x;
    if (t < WBM_ELEMS) {
        int j = t & 7, lane = (t >> 3) & 63, nt = (t >> 9) & 3, kb = t >> 11;
        int k = kb * 32 + ((lane >> 4) << 3) + j;
        int n = nt * 16 + (lane & 15);
        int c = k / 10, tp = k - c * 10;
        ws[t] = (tp < 9) ? f2bf(wgt[n * 576 + c * 9 + tp]) : (unsigned short)0;
    } else if (t < WBM_ELEMS + WBO_ELEMS) {
        int t2 = t - WBM_ELEMS;
        int j = t2 & 7, lane = (t2 >> 3) & 63, nt = (t2 >> 9) & 1, kb = t2 >> 10;
        int k = kb * 32 + ((lane >> 4) << 3) + j;
        int n = nt * 16 + (lane & 15);
        int c = k / 10, tp = k - c * 10;
        ws[t] = (tp < 9 && n < 27) ? f2bf(w_off[n * 576 + c * 9 + tp]) : (unsigned short)0;
    }
}

// ---------------- main kernel ----------------
__global__ __launch_bounds__(256) void DeformConv_14568529068723_kernel(
    const float* __restrict__ x,
    const float* __restrict__ b_off,
    const float* __restrict__ bias,
    const float* __restrict__ gamma,
    const float* __restrict__ beta,
    const float* __restrict__ rmean,
    const float* __restrict__ rvar,
    const unsigned short* __restrict__ ws,
    float* __restrict__ out)
{
    __shared__ __align__(16) unsigned short samp[64 * KPAD];  // 21504 B; reused as dT f32[64][65]
    __shared__ float offs[27 * 64];                           // [oc][px]
    __shared__ float sbuf[176];                               // 0-63 scale, 64-127 bias2, 128-154 b_off

    const int tid  = threadIdx.x;
    const int lane = tid & 63;
    const int wv   = tid >> 6;

    if (tid < 64) {
        float sc = gamma[tid] * __frsqrt_rn(rvar[tid] + 1e-5f);
        sbuf[tid] = sc;
        sbuf[64 + tid] = (bias[tid] - rmean[tid]) * sc + beta[tid];
    }
    if (tid < 27) sbuf[128 + tid] = b_off[tid];

    const int p0   = blockIdx.x * 64;
    const int b    = p0 >> 14;
    const int rem0 = p0 & 16383;
    const int h    = rem0 >> 7;
    const int w    = (rem0 & 127) + lane;      // lane = pixel
    const float* xb = x + ((size_t)b << 20);

    const bf16x8* WbM = (const bf16x8*)ws;
    const bf16x8* WbO = (const bf16x8*)(ws + WBM_ELEMS);

    __syncthreads();

    // ================= offset conv via MFMA (4 chunks of 16 channels) =================
    f32x4 accO0 = {0.f, 0.f, 0.f, 0.f};
    f32x4 accO1 = {0.f, 0.f, 0.f, 0.f};
    for (int cf = 0; cf < 4; ++cf) {
#pragma unroll
        for (int ci = 0; ci < 4; ++ci) {
            int c = cf * 16 + 4 * wv + ci;
            const float* xc = xb + (c << 14);
            float v[10];
            v[9] = 0.f;
#pragma unroll
            for (int t = 0; t < 9; ++t) {
                int yy = h + t / 3 - 1;
                int xx = w + t % 3 - 1;
                bool ok = (yy >= 0) & (yy < HH) & (xx >= 0) & (xx < WW);
                int yc = min(max(yy, 0), HH - 1);
                int xcl = min(max(xx, 0), WW - 1);
                float val = xc[yc * WW + xcl];
                v[t] = ok ? val : 0.f;
            }
            unsigned int* dst = (unsigned int*)&samp[lane * KPAD + (4 * wv + ci) * 10];
#pragma unroll
            for (int tp = 0; tp < 5; ++tp)
                dst[tp] = (unsigned int)f2bf(v[2 * tp]) | ((unsigned int)f2bf(v[2 * tp + 1]) << 16);
        }
        __syncthreads();
#pragma unroll
        for (int st = 0; st < 5; ++st) {
            bf16x8 af = *(const bf16x8*)&samp[(16 * wv + (lane & 15)) * KPAD + st * 32 + ((lane >> 4) << 3)];
            int kb = cf * 5 + st;
            bf16x8 b0 = WbO[(kb * 2 + 0) * 64 + lane];
            bf16x8 b1 = WbO[(kb * 2 + 1) * 64 + lane];
            accO0 = __builtin_amdgcn_mfma_f32_16x16x32_bf16(af, b0, accO0, 0, 0, 0);
            accO1 = __builtin_amdgcn_mfma_f32_16x16x32_bf16(af, b1, accO1, 0, 0, 0);
        }
        __syncthreads();
    }
    // D -> offs[oc][px], + bias, sigmoid masks. n=lane&15, m=(lane>>4)*4+r (+16*wv)
    {
        int n0 = lane & 15;
        int mB = 16 * wv + ((lane >> 4) << 2);
#pragma unroll
        for (int r = 0; r < 4; ++r) {
            offs[n0 * 64 + mB + r] = accO0[r] + sbuf[128 + n0];          // oc 0..15: never sigmoid
            int n1 = 16 + n0;
            if (n1 < 27) {
                float vv = accO1[r] + sbuf[128 + n1];
                if (n1 >= 18) vv = 1.0f / (1.0f + __expf(-vv));
                offs[n1 * 64 + mB + r] = vv;
            }
        }
    }
    __syncthreads();

    // ======== bilinear setup: pair-loads with corner-select folded into weights ========
    // Per tap: rows yc0/yc1 at column pair [bx, bx+1]; e{row}{x,y} are the
    // effective weights of the pair elements (clamp-duplication handled).
    int   o0s[9], o1s[9];
    float e0x[9], e0y[9], e1x[9], e1y[9];
#pragma unroll
    for (int k = 0; k < 9; ++k) {
        float o1 = offs[(2 * k) * 64 + lane];
        float o2 = offs[(2 * k + 1) * 64 + lane];
        float m  = offs[(18 + k) * 64 + lane];
        float py = (float)(h + k / 3 - 1) + o1;
        float px = (float)(w + k % 3 - 1) + o2;
        float y0f = floorf(py), x0f = floorf(px);
        float dy = py - y0f, dx = px - x0f;
        int y0 = (int)y0f, x0 = (int)x0f;
        int y1 = y0 + 1, x1 = x0 + 1;
        int yc0 = min(max(y0, 0), HH - 1), yc1 = min(max(y1, 0), HH - 1);
        int xc0 = min(max(x0, 0), WW - 1), xc1 = min(max(x1, 0), WW - 1);
        float vy0 = (y0 >= 0 && y0 < HH) ? 1.0f : 0.0f;
        float vy1 = (y1 >= 0 && y1 < HH) ? 1.0f : 0.0f;
        float vx0 = (x0 >= 0 && x0 < WW) ? 1.0f : 0.0f;
        float vx1 = (x1 >= 0 && x1 < WW) ? 1.0f : 0.0f;
        float c00 = (1.0f - dy) * (1.0f - dx) * m * vy0 * vx0;
        float c01 = (1.0f - dy) * dx * m * vy0 * vx1;
        float c10 = dy * (1.0f - dx) * m * vy1 * vx0;
        float c11 = dy * dx * m * vy1 * vx1;
        int bx = min(xc0, WW - 2);          // pair [bx, bx+1] always in-bounds
        bool s0 = (xc0 != bx);              // element index of xc0 within pair
        bool s1 = (xc1 != bx);              // element index of xc1 within pair
        e0x[k] = (s0 ? 0.f : c00) + (s1 ? 0.f : c01);
        e0y[k] = (s0 ? c00 : 0.f) + (s1 ? c01 : 0.f);
        e1x[k] = (s0 ? 0.f : c10) + (s1 ? 0.f : c11);
        e1y[k] = (s0 ? c10 : 0.f) + (s1 ? c11 : 0.f);
        o0s[k] = yc0 * WW + bx;
        o1s[k] = yc1 * WW + bx;
    }

    // ================= main conv via MFMA (4 chunks of 16 channels) =================
    f32x4 acc[4];
#pragma unroll
    for (int nt = 0; nt < 4; ++nt) acc[nt] = (f32x4){0.f, 0.f, 0.f, 0.f};

    for (int cf = 0; cf < 4; ++cf) {
#pragma unroll
        for (int ci = 0; ci < 4; ++ci) {
            int c = cf * 16 + 4 * wv + ci;
            const float* xc = xb + (c << 14);
            float sv[10];
            sv[9] = 0.f;
#pragma unroll
            for (int k = 0; k < 9; ++k) {
                f32x2a q0 = *(const f32x2a*)(xc + o0s[k]);   // row yc0: cols bx, bx+1
                f32x2a q1 = *(const f32x2a*)(xc + o1s[k]);   // row yc1
                sv[k] = e0x[k] * q0.x + e0y[k] * q0.y
                      + e1x[k] * q1.x + e1y[k] * q1.y;
            }
            unsigned int* dst = (unsigned int*)&samp[lane * KPAD + (4 * wv + ci) * 10];
#pragma unroll
            for (int tp = 0; tp < 5; ++tp)
                dst[tp] = (unsigned int)f2bf(sv[2 * tp]) | ((unsigned int)f2bf(sv[2 * tp + 1]) << 16);
        }
        __syncthreads();
#pragma unroll
        for (int st = 0; st < 5; ++st) {
            bf16x8 af = *(const bf16x8*)&samp[(16 * wv + (lane & 15)) * KPAD + st * 32 + ((lane >> 4) << 3)];
            int kb = cf * 5 + st;
#pragma unroll
            for (int nt = 0; nt < 4; ++nt) {
                bf16x8 bf = WbM[(kb * 4 + nt) * 64 + lane];
                acc[nt] = __builtin_amdgcn_mfma_f32_16x16x32_bf16(af, bf, acc[nt], 0, 0, 0);
            }
        }
        __syncthreads();
    }

    // ================= epilogue: transpose via LDS, BN + ReLU, coalesced stores ==========
    float* dT = (float*)samp;   // [64 o][65]; 16640 B <= 21504 B
    {
        int n0 = lane & 15;
        int mB = 16 * wv + ((lane >> 4) << 2);
#pragma unroll
        for (int nt = 0; nt < 4; ++nt)
#pragma unroll
            for (int r = 0; r < 4; ++r)
                dT[(nt * 16 + n0) * 65 + mB + r] = acc[nt][r];
    }
    __syncthreads();
#pragma unroll
    for (int i = 0; i < 16; ++i) {
        int o = 16 * wv + i;
        float v = dT[o * 65 + lane];
        v = fmaxf(fmaf(v, sbuf[o], sbuf[64 + o]), 0.0f);
        out[(((size_t)(b * 64 + o)) << 14) + rem0 + lane] = v;
    }
}

extern "C" void kernel_launch(void* const* d_in, const int* in_sizes, int n_in,
                              void* d_out, int out_size, void* d_ws, size_t ws_size,
                              hipStream_t stream) {
    (void)in_sizes; (void)n_in; (void)ws_size; (void)out_size;
    const float* x     = (const float*)d_in[0];
    const float* w_off = (const float*)d_in[1];
    const float* b_off = (const float*)d_in[2];
    const float* wgt   = (const float*)d_in[3];
    const float* bias  = (const float*)d_in[4];
    const float* gamma = (const float*)d_in[5];
    const float* beta  = (const float*)d_in[6];
    const float* rmean = (const float*)d_in[7];
    const float* rvar  = (const float*)d_in[8];
    unsigned short* wsB = (unsigned short*)d_ws;
    float* outp = (float*)d_out;

    prep_kernel<<<dim3(240), dim3(256), 0, stream>>>(w_off, wgt, wsB);
    DeformConv_14568529068723_kernel<<<dim3(1024), dim3(256), 0, stream>>>(
        x, b_off, bias, gamma, beta, rmean, rvar, wsB, outp);
}

// Round 11
// 187.175 us; speedup vs baseline: 1.2003x; 1.0249x over previous
//
#include <hip/hip_runtime.h>
#include <hip/hip_bf16.h>

// DCN v2 (modulated deformable 3x3 conv) + BN(eval) + ReLU, fused, MFMA version.
// B=4, C=64, O=64, H=W=128. fp32 in/out; bf16 MFMA (16x16x32) w/ fp32 accum.
//
// R11: ONE WAVE PER BLOCK (64 threads, 16 pixels). R10's 4-wave blocks were
// barrier-coupled (18 syncs chaining all 4 waves to the slowest gather burst;
// effective occupancy 7 waves/CU despite capacity 16). Per-wave work identical
// to R10: lane = (cg=lane>>4, px=lane&15); wave owns the full M=16 GEMM tile.
// Barriers now intra-wave (nearly free); 16 independent waves/CU.
//
// GEMM (K = c*10+tap, taps padded 9->10, 4 chunks of 16 ch, K=640 total):
//   offset conv: [16px x 576] x [576 x 27->32]
//   main conv  : [16px x 576] x [576 x 64]
// A staged in LDS bf16 [16 px][KPAD=168] per chunk; B pre-swizzled in d_ws:
// Wb[kb][nt][lane][j] = W[k=kb*32+(lane>>4)*8+j][n=nt*16+(lane&15)].
// MFMA layouts (m89/m120-verified): A[m=lane&15][k=(lane>>4)*8+j];
// B[k=(lane>>4)*8+j][n=lane&15]; D: n=lane&15, m=(lane>>4)*4+reg.
//
// REGISTER NOTE (R4-R7): plain __launch_bounds__ ONLY; any min-waves arg
// triggers catastrophic scratch spill.

#define HH 128
#define WW 128
#define KPAD 168            // 160 + 8 pad ushorts; 336 B rows (16-B aligned)

typedef __attribute__((ext_vector_type(8))) short bf16x8;
typedef __attribute__((ext_vector_type(4))) float f32x4;
typedef float f32x2a __attribute__((ext_vector_type(2), aligned(4)));  // 4B-aligned pair load

__device__ __forceinline__ unsigned short f2bf(float f) {
    union { __hip_bfloat16 b; unsigned short u; } cv;
    cv.b = __float2bfloat16(f);
    return cv.u;
}

// ws layout (ushort): WbM[20][4][64][8] = 40960 | WbO[20][2][64][8] = 20480
#define WBM_ELEMS 40960
#define WBO_ELEMS 20480

// ---------------- prep: swizzle weights into B-fragment order, bf16 ----------------
__global__ __launch_bounds__(256) void prep_kernel(
    const float* __restrict__ w_off,
    const float* __restrict__ wgt,
    unsigned short* __restrict__ ws)
{
    int t = blockIdx.x * 256 + threadIdx.x;
    if (t < WBM_ELEMS) {
        int j = t & 7, lane = (t >> 3) & 63, nt = (t >> 9) & 3, kb = t >> 11;
        int k = kb * 32 + ((lane >> 4) << 3) + j;
        int n = nt * 16 + (lane & 15);
        int c = k / 10, tp = k - c * 10;
        ws[t] = (tp < 9) ? f2bf(wgt[n * 576 + c * 9 + tp]) : (unsigned short)0;
    } else if (t < WBM_ELEMS + WBO_ELEMS) {
        int t2 = t - WBM_ELEMS;
        int j = t2 & 7, lane = (t2 >> 3) & 63, nt = (t2 >> 9) & 1, kb = t2 >> 10;
        int k = kb * 32 + ((lane >> 4) << 3) + j;
        int n = nt * 16 + (lane & 15);
        int c = k / 10, tp = k - c * 10;
        ws[t] = (tp < 9 && n < 27) ? f2bf(w_off[n * 576 + c * 9 + tp]) : (unsigned short)0;
    }
}

// ---------------- main kernel: 1 wave / 16 pixels per block ----------------
__global__ __launch_bounds__(64) void DeformConv_14568529068723_kernel(
    const float* __restrict__ x,
    const float* __restrict__ b_off,
    const float* __restrict__ bias,
    const float* __restrict__ gamma,
    const float* __restrict__ beta,
    const float* __restrict__ rmean,
    const float* __restrict__ rvar,
    const unsigned short* __restrict__ ws,
    float* __restrict__ out)
{
    __shared__ __align__(16) unsigned short samp[16 * KPAD];  // 5376 B; aliased as dT f32[64][17]
    __shared__ float offs[27 * 16];                           // [oc][px]
    __shared__ float sbuf[176];                               // 0-63 scale, 64-127 bias2, 128-154 b_off

    const int tid = threadIdx.x;
    const int px  = tid & 15;     // pixel within block
    const int cg  = tid >> 4;     // channel group / MFMA k-quad

    {
        float sc = gamma[tid] * __frsqrt_rn(rvar[tid] + 1e-5f);
        sbuf[tid] = sc;
        sbuf[64 + tid] = (bias[tid] - rmean[tid]) * sc + beta[tid];
        if (tid < 27) sbuf[128 + tid] = b_off[tid];
    }

    const int p0   = blockIdx.x * 16;
    const int b    = p0 >> 14;
    const int rem0 = p0 & 16383;
    const int h    = rem0 >> 7;
    const int w    = (rem0 & 127) + px;
    const float* xb = x + ((size_t)b << 20);

    const bf16x8* WbM = (const bf16x8*)ws;
    const bf16x8* WbO = (const bf16x8*)(ws + WBM_ELEMS);

    __syncthreads();

    // ================= offset conv via MFMA (4 chunks of 16 channels) =================
    f32x4 accO0 = {0.f, 0.f, 0.f, 0.f};
    f32x4 accO1 = {0.f, 0.f, 0.f, 0.f};
    for (int cf = 0; cf < 4; ++cf) {
#pragma unroll
        for (int ci = 0; ci < 4; ++ci) {
            int c = cf * 16 + cg * 4 + ci;
            const float* xc = xb + (c << 14);
            float v[10];
            v[9] = 0.f;
#pragma unroll
            for (int t = 0; t < 9; ++t) {
                int yy = h + t / 3 - 1;
                int xx = w + t % 3 - 1;
                bool ok = (yy >= 0) & (yy < HH) & (xx >= 0) & (xx < WW);
                int yc = min(max(yy, 0), HH - 1);
                int xcl = min(max(xx, 0), WW - 1);
                float val = xc[yc * WW + xcl];
                v[t] = ok ? val : 0.f;
            }
            unsigned int* dst = (unsigned int*)&samp[px * KPAD + (cg * 4 + ci) * 10];
#pragma unroll
            for (int tp = 0; tp < 5; ++tp)
                dst[tp] = (unsigned int)f2bf(v[2 * tp]) | ((unsigned int)f2bf(v[2 * tp + 1]) << 16);
        }
        __syncthreads();
#pragma unroll
        for (int st = 0; st < 5; ++st) {
            bf16x8 af = *(const bf16x8*)&samp[px * KPAD + st * 32 + cg * 8];
            int kb = cf * 5 + st;
            bf16x8 b0 = WbO[(kb * 2 + 0) * 64 + tid];
            bf16x8 b1 = WbO[(kb * 2 + 1) * 64 + tid];
            accO0 = __builtin_amdgcn_mfma_f32_16x16x32_bf16(af, b0, accO0, 0, 0, 0);
            accO1 = __builtin_amdgcn_mfma_f32_16x16x32_bf16(af, b1, accO1, 0, 0, 0);
        }
        __syncthreads();
    }
    // D -> offs[oc][px], + bias, sigmoid masks. n=tid&15, m(px)=cg*4+r
    {
        int n0 = tid & 15;
        int mB = cg * 4;
#pragma unroll
        for (int r = 0; r < 4; ++r) {
            offs[n0 * 16 + mB + r] = accO0[r] + sbuf[128 + n0];          // oc 0..15: never sigmoid
            int n1 = 16 + n0;
            if (n1 < 27) {
                float vv = accO1[r] + sbuf[128 + n1];
                if (n1 >= 18) vv = 1.0f / (1.0f + __expf(-vv));
                offs[n1 * 16 + mB + r] = vv;
            }
        }
    }
    __syncthreads();

    // ======== bilinear setup: pair-loads with corner-select folded into weights ========
    int   o0s[9], o1s[9];
    float e0x[9], e0y[9], e1x[9], e1y[9];
#pragma unroll
    for (int k = 0; k < 9; ++k) {
        float o1 = offs[(2 * k) * 16 + px];
        float o2 = offs[(2 * k + 1) * 16 + px];
        float m  = offs[(18 + k) * 16 + px];
        float py = (float)(h + k / 3 - 1) + o1;
        float pxf = (float)(w + k % 3 - 1) + o2;
        float y0f = floorf(py), x0f = floorf(pxf);
        float dy = py - y0f, dx = pxf - x0f;
        int y0 = (int)y0f, x0 = (int)x0f;
        int y1 = y0 + 1, x1 = x0 + 1;
        int yc0 = min(max(y0, 0), HH - 1), yc1 = min(max(y1, 0), HH - 1);
        int xc0 = min(max(x0, 0), WW - 1), xc1 = min(max(x1, 0), WW - 1);
        float vy0 = (y0 >= 0 && y0 < HH) ? 1.0f : 0.0f;
        float vy1 = (y1 >= 0 && y1 < HH) ? 1.0f : 0.0f;
        float vx0 = (x0 >= 0 && x0 < WW) ? 1.0f : 0.0f;
        float vx1 = (x1 >= 0 && x1 < WW) ? 1.0f : 0.0f;
        float c00 = (1.0f - dy) * (1.0f - dx) * m * vy0 * vx0;
        float c01 = (1.0f - dy) * dx * m * vy0 * vx1;
        float c10 = dy * (1.0f - dx) * m * vy1 * vx0;
        float c11 = dy * dx * m * vy1 * vx1;
        int bx = min(xc0, WW - 2);          // pair [bx, bx+1] always in-bounds
        bool s0 = (xc0 != bx);
        bool s1 = (xc1 != bx);
        e0x[k] = (s0 ? 0.f : c00) + (s1 ? 0.f : c01);
        e0y[k] = (s0 ? c00 : 0.f) + (s1 ? c01 : 0.f);
        e1x[k] = (s0 ? 0.f : c10) + (s1 ? 0.f : c11);
        e1y[k] = (s0 ? c10 : 0.f) + (s1 ? c11 : 0.f);
        o0s[k] = yc0 * WW + bx;
        o1s[k] = yc1 * WW + bx;
    }

    // ================= main conv via MFMA (4 chunks of 16 channels) =================
    f32x4 acc[4];
#pragma unroll
    for (int nt = 0; nt < 4; ++nt) acc[nt] = (f32x4){0.f, 0.f, 0.f, 0.f};

    for (int cf = 0; cf < 4; ++cf) {
#pragma unroll
        for (int ci = 0; ci < 4; ++ci) {
            int c = cf * 16 + cg * 4 + ci;
            const float* xc = xb + (c << 14);
            float sv[10];
            sv[9] = 0.f;
#pragma unroll
            for (int k = 0; k < 9; ++k) {
                f32x2a q0 = *(const f32x2a*)(xc + o0s[k]);   // row yc0: cols bx, bx+1
                f32x2a q1 = *(const f32x2a*)(xc + o1s[k]);   // row yc1
                sv[k] = e0x[k] * q0.x + e0y[k] * q0.y
                      + e1x[k] * q1.x + e1y[k] * q1.y;
            }
            unsigned int* dst = (unsigned int*)&samp[px * KPAD + (cg * 4 + ci) * 10];
#pragma unroll
            for (int tp = 0; tp < 5; ++tp)
                dst[tp] = (unsigned int)f2bf(sv[2 * tp]) | ((unsigned int)f2bf(sv[2 * tp + 1]) << 16);
        }
        __syncthreads();
#pragma unroll
        for (int st = 0; st < 5; ++st) {
            bf16x8 af = *(const bf16x8*)&samp[px * KPAD + st * 32 + cg * 8];
            int kb = cf * 5 + st;
#pragma unroll
            for (int nt = 0; nt < 4; ++nt) {
                bf16x8 bf = WbM[(kb * 4 + nt) * 64 + tid];
                acc[nt] = __builtin_amdgcn_mfma_f32_16x16x32_bf16(af, bf, acc[nt], 0, 0, 0);
            }
        }
        __syncthreads();
    }

    // ================= epilogue: transpose via LDS, BN + ReLU, coalesced stores ==========
    float* dT = (float*)samp;   // [64 o][17 px-padded]; 4352 B <= 5376 B
    {
        int n0 = tid & 15;
#pragma unroll
        for (int nt = 0; nt < 4; ++nt)
#pragma unroll
            for (int r = 0; r < 4; ++r)
                dT[(nt * 16 + n0) * 17 + cg * 4 + r] = acc[nt][r];
    }
    __syncthreads();
#pragma unroll
    for (int i = 0; i < 16; ++i) {
        int o = 4 * i + cg;
        float v = dT[o * 17 + px];
        v = fmaxf(fmaf(v, sbuf[o], sbuf[64 + o]), 0.0f);
        out[(((size_t)(b * 64 + o)) << 14) + rem0 + px] = v;
    }
}

extern "C" void kernel_launch(void* const* d_in, const int* in_sizes, int n_in,
                              void* d_out, int out_size, void* d_ws, size_t ws_size,
                              hipStream_t stream) {
    (void)in_sizes; (void)n_in; (void)ws_size; (void)out_size;
    const float* x     = (const float*)d_in[0];
    const float* w_off = (const float*)d_in[1];
    const float* b_off = (const float*)d_in[2];
    const float* wgt   = (const float*)d_in[3];
    const float* bias  = (const float*)d_in[4];
    const float* gamma = (const float*)d_in[5];
    const float* beta  = (const float*)d_in[6];
    const float* rmean = (const float*)d_in[7];
    const float* rvar  = (const float*)d_in[8];
    unsigned short* wsB = (unsigned short*)d_ws;
    float* outp = (float*)d_out;

    prep_kernel<<<dim3(240), dim3(256), 0, stream>>>(w_off, wgt, wsB);
    // 65536 px / 16 per block = 4096 blocks of 64 threads (1 wave each)
    DeformConv_14568529068723_kernel<<<dim3(4096), dim3(64), 0, stream>>>(
        x, b_off, bias, gamma, beta, rmean, rvar, wsB, outp);
}

// Round 12
// 152.153 us; speedup vs baseline: 1.4766x; 1.2302x over previous
//
#include <hip/hip_runtime.h>
#include <hip/hip_bf16.h>

// DCN v2 (modulated deformable 3x3 conv) + BN(eval) + ReLU, fused, MFMA.
// B=4, C=64, O=64, H=W=128. fp32 in/out; bf16 MFMA 16x16x32, fp32 accum.
//
// R12: NHWC GATHERING. R9-R11 proved the kernel is bound by the TA pipe
// serializing divergent NCHW gathers (time tracked VMEM-instruction count;
// VALU/MFMA/HBM all idle; occupancy-insensitive). New structure:
//   1) transpose kernel: x NCHW fp32 -> xT NHWC bf16 in d_ws (8.4MB).
//      In NHWC all 64 ch of a (y,x) position are 128B contiguous; the two
//      bilinear corner COLUMNS are adjacent -> 256B contiguous per row.
//   2) K-layout now TAP-MAJOR: k = tap*64 + c, K = 576 exact (no padding).
//      Staged A-values are channel-contiguous -> ds_write_b64.
//   3) lane = (pxq=lane>>4, c4=lane&15): each gather instruction covers 4
//      consecutive pixels x 16 ch-quads = 4 contiguous 128B segments.
//   4) bilinear weights/offsets precomputed per (px,tap) into LDS
//      (broadcast reads), freeing ~50 VGPRs vs R11.
// Blocks: 1 wave, 16 px (R11 structure). Grid 4096.
//
// MFMA layouts (m89/m120-verified): A[m=lane&15][k=(lane>>4)*8+j];
// B[k=(lane>>4)*8+j][n=lane&15]; D: n=lane&15, m=(lane>>4)*4+reg.
// B-frags pre-swizzled in d_ws: Wb[kb][nt][lane][j] =
//   W[k=kb*32+(lane>>4)*8+j][n=nt*16+(lane&15)], k tap-major.
//
// REGISTER NOTE (R4-R7): plain __launch_bounds__ ONLY; min-waves args cause
// catastrophic scratch spill.

#define HH 128
#define WW 128
#define KP2 200   // samp row stride (ushorts): 192 data + 8 pad; 400B rows (16B-aligned)

typedef __attribute__((ext_vector_type(8))) short bf16x8;
typedef __attribute__((ext_vector_type(4))) float f32x4;

__device__ __forceinline__ unsigned short f2bf(float f) {
    union { __hip_bfloat16 b; unsigned short u; } cv;
    cv.b = __float2bfloat16(f);
    return cv.u;
}
__device__ __forceinline__ float bf2f(unsigned short u) {
    union { unsigned int i; float f; } cv;
    cv.i = ((unsigned int)u) << 16;
    return cv.f;
}

// ws layout (ushort):
//   [0, 36864)          WbM [18][4][64][8]
//   [36864, 55296)      WbO [18][2][64][8]
//   [55296, 55296+4.2M) xT  [4][128][128][64] bf16 NHWC
// total 8,499,200 bytes.
#define WBM_ELEMS 36864
#define WBO_ELEMS 18432
#define XT_OFF    55296

// ---------------- prep: swizzle weights into B-fragment order (tap-major K) ----------------
__global__ __launch_bounds__(256) void prep_kernel(
    const float* __restrict__ w_off,
    const float* __restrict__ wgt,
    unsigned short* __restrict__ ws)
{
    int t = blockIdx.x * 256 + threadIdx.x;
    if (t < WBM_ELEMS) {
        int j = t & 7, lane = (t >> 3) & 63, nt = (t >> 9) & 3, kb = t >> 11;
        int k = kb * 32 + ((lane >> 4) << 3) + j;
        int n = nt * 16 + (lane & 15);
        int tap = k >> 6, c = k & 63;
        ws[t] = f2bf(wgt[n * 576 + c * 9 + tap]);
    } else if (t < WBM_ELEMS + WBO_ELEMS) {
        int t2 = t - WBM_ELEMS;
        int j = t2 & 7, lane = (t2 >> 3) & 63, nt = (t2 >> 9) & 1, kb = t2 >> 10;
        int k = kb * 32 + ((lane >> 4) << 3) + j;
        int n = nt * 16 + (lane & 15);
        int tap = k >> 6, c = k & 63;
        ws[t] = (n < 27) ? f2bf(w_off[n * 576 + c * 9 + tap]) : (unsigned short)0;
    }
}

// ---------------- transpose: NCHW fp32 -> NHWC bf16 ----------------
__global__ __launch_bounds__(256) void transpose_kernel(
    const float* __restrict__ x,
    unsigned short* __restrict__ ws)
{
    __shared__ float tile[64 * 65];
    const int bb  = blockIdx.x >> 8;
    const int hw0 = (blockIdx.x & 255) << 6;
    const int tid = threadIdx.x;
    const float* xb = x + ((size_t)bb << 20);
#pragma unroll
    for (int it = 0; it < 16; ++it) {
        int idx = it * 256 + tid;
        int c = idx >> 6, i = idx & 63;
        tile[c * 65 + i] = xb[(c << 14) + hw0 + i];   // coalesced in i
    }
    __syncthreads();
    unsigned int* xtb = (unsigned int*)(ws + XT_OFF) + ((size_t)bb << 19);
#pragma unroll
    for (int it = 0; it < 8; ++it) {
        int idx = it * 256 + tid;
        int i = idx >> 5, c2 = idx & 31;
        unsigned int lo = (unsigned int)f2bf(tile[(2 * c2) * 65 + i]);
        unsigned int hi = (unsigned int)f2bf(tile[(2 * c2 + 1) * 65 + i]);
        xtb[(size_t)(hw0 + i) * 32 + c2] = lo | (hi << 16);   // coalesced in c2
    }
}

// ---------------- main kernel: 1 wave / 16 pixels per block ----------------
__global__ __launch_bounds__(64) void DeformConv_14568529068723_kernel(
    const float* __restrict__ b_off,
    const float* __restrict__ bias,
    const float* __restrict__ gamma,
    const float* __restrict__ beta,
    const float* __restrict__ rmean,
    const float* __restrict__ rvar,
    const unsigned short* __restrict__ ws,
    float* __restrict__ out)
{
    __shared__ __align__(16) unsigned short samp[16 * KP2];  // 6400B; aliased as dT f32[64][17]
    __shared__ float offs[27 * 16];      // [oc][px]
    __shared__ float eL[4][9][16];       // e0x,e0y,e1x,e1y per (tap,px)
    __shared__ int   oL[2][9][16];       // row0/row1 base element offsets
    __shared__ float sbuf[176];          // 0-63 scale, 64-127 bias2, 128-154 b_off

    const int tid  = threadIdx.x;
    const int px16 = tid & 15;           // MFMA m-lane / epilogue px
    const int cg   = tid >> 4;           // MFMA k-quad
    const int c16  = tid & 15;           // staging: channel quad (4 ch)
    const int pxq  = tid >> 4;           // staging: px sub-index

    {
        float sc = gamma[tid] * __frsqrt_rn(rvar[tid] + 1e-5f);
        sbuf[tid] = sc;
        sbuf[64 + tid] = (bias[tid] - rmean[tid]) * sc + beta[tid];
        if (tid < 27) sbuf[128 + tid] = b_off[tid];
    }

    const int p0   = blockIdx.x * 16;
    const int b    = p0 >> 14;
    const int rem0 = p0 & 16383;
    const int h    = rem0 >> 7;
    const int w0   = rem0 & 127;
    const unsigned short* xt = ws + XT_OFF + ((size_t)b << 20);  // b*16384*64

    const bf16x8* WbM = (const bf16x8*)ws;
    const bf16x8* WbO = (const bf16x8*)(ws + WBM_ELEMS);

    __syncthreads();

    // ================= offset conv via MFMA (3 chunks of 3 taps) =================
    f32x4 accO0 = {0.f, 0.f, 0.f, 0.f};
    f32x4 accO1 = {0.f, 0.f, 0.f, 0.f};
    for (int chk = 0; chk < 3; ++chk) {
#pragma unroll
        for (int tl = 0; tl < 3; ++tl) {
            int tap = chk * 3 + tl;
            int ky = tap / 3 - 1, kx = tap % 3 - 1;
            int yy = h + ky;
            int yc = min(max(yy, 0), HH - 1);
            bool oky = (yy >= 0) & (yy < HH);
#pragma unroll
            for (int it = 0; it < 4; ++it) {
                int px = it * 4 + pxq;
                int xx = w0 + px + kx;
                bool ok = oky & (xx >= 0) & (xx < WW);
                int pos = yc * WW + min(max(xx, 0), WW - 1);
                uint2 v = *(const uint2*)(xt + pos * 64 + (c16 << 2));
                if (!ok) { v.x = 0u; v.y = 0u; }
                *(uint2*)&samp[px * KP2 + tl * 64 + (c16 << 2)] = v;
            }
        }
        __syncthreads();
#pragma unroll
        for (int st = 0; st < 6; ++st) {
            bf16x8 af = *(const bf16x8*)&samp[px16 * KP2 + st * 32 + (cg << 3)];
            int kb = chk * 6 + st;
            bf16x8 b0 = WbO[(kb * 2 + 0) * 64 + tid];
            bf16x8 b1 = WbO[(kb * 2 + 1) * 64 + tid];
            accO0 = __builtin_amdgcn_mfma_f32_16x16x32_bf16(af, b0, accO0, 0, 0, 0);
            accO1 = __builtin_amdgcn_mfma_f32_16x16x32_bf16(af, b1, accO1, 0, 0, 0);
        }
        __syncthreads();
    }
    // D -> offs[oc][px], + bias, sigmoid masks. n=tid&15, m(px)=cg*4+r
    {
        int n0 = tid & 15;
        int mB = cg * 4;
#pragma unroll
        for (int r = 0; r < 4; ++r) {
            offs[n0 * 16 + mB + r] = accO0[r] + sbuf[128 + n0];   // oc 0..15: never sigmoid
            int n1 = 16 + n0;
            if (n1 < 27) {
                float vv = accO1[r] + sbuf[128 + n1];
                if (n1 >= 18) vv = 1.0f / (1.0f + __expf(-vv));
                offs[n1 * 16 + mB + r] = vv;
            }
        }
    }
    __syncthreads();

    // ========= bilinear setup per (px,tap) -> LDS (corner-select folded into e-weights) =========
#pragma unroll
    for (int it2 = 0; it2 < 3; ++it2) {
        int idx = it2 * 64 + tid;
        if (idx < 144) {
            int px = idx & 15, tap = idx >> 4;
            float o1 = offs[(2 * tap) * 16 + px];
            float o2 = offs[(2 * tap + 1) * 16 + px];
            float m  = offs[(18 + tap) * 16 + px];
            float py  = (float)(h + tap / 3 - 1) + o1;
            float pxf = (float)(w0 + px + tap % 3 - 1) + o2;
            float y0f = floorf(py), x0f = floorf(pxf);
            float dy = py - y0f, dx = pxf - x0f;
            int y0 = (int)y0f, x0 = (int)x0f;
            int y1 = y0 + 1, x1 = x0 + 1;
            int yc0 = min(max(y0, 0), HH - 1), yc1 = min(max(y1, 0), HH - 1);
            int xc0 = min(max(x0, 0), WW - 1), xc1 = min(max(x1, 0), WW - 1);
            float vy0 = (y0 >= 0 && y0 < HH) ? 1.0f : 0.0f;
            float vy1 = (y1 >= 0 && y1 < HH) ? 1.0f : 0.0f;
            float vx0 = (x0 >= 0 && x0 < WW) ? 1.0f : 0.0f;
            float vx1 = (x1 >= 0 && x1 < WW) ? 1.0f : 0.0f;
            float c00 = (1.0f - dy) * (1.0f - dx) * m * vy0 * vx0;
            float c01 = (1.0f - dy) * dx * m * vy0 * vx1;
            float c10 = dy * (1.0f - dx) * m * vy1 * vx0;
            float c11 = dy * dx * m * vy1 * vx1;
            int bx = min(xc0, WW - 2);        // column pair [bx, bx+1] always in-bounds
            bool s0 = (xc0 != bx), s1 = (xc1 != bx);
            eL[0][tap][px] = (s0 ? 0.f : c00) + (s1 ? 0.f : c01);  // row0, col bx
            eL[1][tap][px] = (s0 ? c00 : 0.f) + (s1 ? c01 : 0.f);  // row0, col bx+1
            eL[2][tap][px] = (s0 ? 0.f : c10) + (s1 ? 0.f : c11);  // row1, col bx
            eL[3][tap][px] = (s0 ? c10 : 0.f) + (s1 ? c11 : 0.f);  // row1, col bx+1
            oL[0][tap][px] = (yc0 * WW + bx) * 64;
            oL[1][tap][px] = (yc1 * WW + bx) * 64;
        }
    }
    __syncthreads();

    // ================= main conv via MFMA (3 chunks of 3 taps) =================
    f32x4 acc[4];
#pragma unroll
    for (int nt = 0; nt < 4; ++nt) acc[nt] = (f32x4){0.f, 0.f, 0.f, 0.f};

    for (int chk = 0; chk < 3; ++chk) {
#pragma unroll
        for (int tl = 0; tl < 3; ++tl) {
            int tap = chk * 3 + tl;
#pragma unroll
            for (int it = 0; it < 4; ++it) {
                int px = it * 4 + pxq;
                int o0 = oL[0][tap][px], o1r = oL[1][tap][px];
                float e0 = eL[0][tap][px], e1 = eL[1][tap][px];
                float e2 = eL[2][tap][px], e3 = eL[3][tap][px];
                uint2 a0 = *(const uint2*)(xt + o0 + (c16 << 2));        // row0 col bx  (4 ch)
                uint2 a1 = *(const uint2*)(xt + o0 + 64 + (c16 << 2));   // row0 col bx+1
                uint2 b0 = *(const uint2*)(xt + o1r + (c16 << 2));       // row1 col bx
                uint2 b1 = *(const uint2*)(xt + o1r + 64 + (c16 << 2));  // row1 col bx+1
                float sv0 = e0 * bf2f((unsigned short)(a0.x & 0xffff))
                          + e1 * bf2f((unsigned short)(a1.x & 0xffff))
                          + e2 * bf2f((unsigned short)(b0.x & 0xffff))
                          + e3 * bf2f((unsigned short)(b1.x & 0xffff));
                float sv1 = e0 * bf2f((unsigned short)(a0.x >> 16))
                          + e1 * bf2f((unsigned short)(a1.x >> 16))
                          + e2 * bf2f((unsigned short)(b0.x >> 16))
                          + e3 * bf2f((unsigned short)(b1.x >> 16));
                float sv2 = e0 * bf2f((unsigned short)(a0.y & 0xffff))
                          + e1 * bf2f((unsigned short)(a1.y & 0xffff))
                          + e2 * bf2f((unsigned short)(b0.y & 0xffff))
                          + e3 * bf2f((unsigned short)(b1.y & 0xffff));
                float sv3 = e0 * bf2f((unsigned short)(a0.y >> 16))
                          + e1 * bf2f((unsigned short)(a1.y >> 16))
                          + e2 * bf2f((unsigned short)(b0.y >> 16))
                          + e3 * bf2f((unsigned short)(b1.y >> 16));
                uint2 pk;
                pk.x = (unsigned int)f2bf(sv0) | ((unsigned int)f2bf(sv1) << 16);
                pk.y = (unsigned int)f2bf(sv2) | ((unsigned int)f2bf(sv3) << 16);
                *(uint2*)&samp[px * KP2 + tl * 64 + (c16 << 2)] = pk;
            }
        }
        __syncthreads();
#pragma unroll
        for (int st = 0; st < 6; ++st) {
            bf16x8 af = *(const bf16x8*)&samp[px16 * KP2 + st * 32 + (cg << 3)];
            int kb = chk * 6 + st;
#pragma unroll
            for (int nt = 0; nt < 4; ++nt) {
                bf16x8 bf = WbM[(kb * 4 + nt) * 64 + tid];
                acc[nt] = __builtin_amdgcn_mfma_f32_16x16x32_bf16(af, bf, acc[nt], 0, 0, 0);
            }
        }
        __syncthreads();
    }

    // ================= epilogue: transpose via LDS, BN + ReLU, coalesced stores ==========
    float* dT = (float*)samp;   // [64 o][17]; 4352B <= 6400B
    {
        int n0 = tid & 15;
#pragma unroll
        for (int nt = 0; nt < 4; ++nt)
#pragma unroll
            for (int r = 0; r < 4; ++r)
                dT[(nt * 16 + n0) * 17 + cg * 4 + r] = acc[nt][r];
    }
    __syncthreads();
#pragma unroll
    for (int i = 0; i < 16; ++i) {
        int o = 4 * i + cg;
        float v = dT[o * 17 + px16];
        v = fmaxf(fmaf(v, sbuf[o], sbuf[64 + o]), 0.0f);
        out[(((size_t)(b * 64 + o)) << 14) + rem0 + px16] = v;
    }
}

extern "C" void kernel_launch(void* const* d_in, const int* in_sizes, int n_in,
                              void* d_out, int out_size, void* d_ws, size_t ws_size,
                              hipStream_t stream) {
    (void)in_sizes; (void)n_in; (void)ws_size; (void)out_size;
    const float* x     = (const float*)d_in[0];
    const float* w_off = (const float*)d_in[1];
    const float* b_off = (const float*)d_in[2];
    const float* wgt   = (const float*)d_in[3];
    const float* bias  = (const float*)d_in[4];
    const float* gamma = (const float*)d_in[5];
    const float* beta  = (const float*)d_in[6];
    const float* rmean = (const float*)d_in[7];
    const float* rvar  = (const float*)d_in[8];
    unsigned short* wsB = (unsigned short*)d_ws;
    float* outp = (float*)d_out;

    prep_kernel<<<dim3(216), dim3(256), 0, stream>>>(w_off, wgt, wsB);
    transpose_kernel<<<dim3(1024), dim3(256), 0, stream>>>(x, wsB);
    // 65536 px / 16 per block = 4096 blocks of 64 threads (1 wave each)
    DeformConv_14568529068723_kernel<<<dim3(4096), dim3(64), 0, stream>>>(
        b_off, bias, gamma, beta, rmean, rvar, wsB, outp);
}

// Round 13
// 126.888 us; speedup vs baseline: 1.7706x; 1.1991x over previous
//
#include <hip/hip_runtime.h>
#include <hip/hip_bf16.h>

// DCN v2 (modulated deformable 3x3 conv) + BN(eval) + ReLU, fused, MFMA.
// B=4, C=64, O=64, H=W=128. fp32 in/out; bf16 MFMA 16x16x32, fp32 accum.
//
// R13: law from R10-R12: time ~ VMEM gather-instruction count. This round:
//   - uint4 gathers: lane=(pxq=tid>>3, c8=tid&7), 8 ch per load ->
//     phase-C corner loads halve; phase-A halves.
//   - M=32 px per wave (2 MFMA M-tiles, grid 2048): weight B-frag loads
//     (108/wave, identical across waves) amortize 2x per pixel.
//   - prep merged into transpose kernel (2 launches total).
// Per-16px VMEM: 288 (R12) -> 144.
//
// NHWC xT bf16 in d_ws; K tap-major (k=tap*64+c, K=576).
// MFMA layouts (m89/m120-verified): A[m=lane&15][k=(lane>>4)*8+j];
// B[k=(lane>>4)*8+j][n=lane&15]; D: n=lane&15, m=(lane>>4)*4+reg.
// B-frags pre-swizzled: Wb[kb][nt][lane][j] = W[k=kb*32+(lane>>4)*8+j][n=nt*16+(lane&15)].
//
// REGISTER NOTE (R4-R7): plain __launch_bounds__ ONLY; min-waves args cause
// catastrophic scratch spill.

#define HH 128
#define WW 128
#define KP2 200   // samp row stride (ushorts): 192 data + 8 pad; 400B rows (16B-aligned)

typedef __attribute__((ext_vector_type(8))) short bf16x8;
typedef __attribute__((ext_vector_type(4))) float f32x4;

__device__ __forceinline__ unsigned short f2bf(float f) {
    union { __hip_bfloat16 b; unsigned short u; } cv;
    cv.b = __float2bfloat16(f);
    return cv.u;
}
__device__ __forceinline__ float bf2f(unsigned short u) {
    union { unsigned int i; float f; } cv;
    cv.i = ((unsigned int)u) << 16;
    return cv.f;
}

// ws layout (ushort):
//   [0, 36864)          WbM [18][4][64][8]
//   [36864, 55296)      WbO [18][2][64][8]
//   [55296, +4.19M)     xT  [4][128][128][64] bf16 NHWC
#define WBM_ELEMS 36864
#define WBO_ELEMS 18432
#define XT_OFF    55296

// ------- transpose (NCHW fp32 -> NHWC bf16) + weight swizzle, merged -------
__global__ __launch_bounds__(256) void transpose_kernel(
    const float* __restrict__ x,
    const float* __restrict__ w_off,
    const float* __restrict__ wgt,
    unsigned short* __restrict__ ws)
{
    __shared__ float tile[64 * 65];
    const int tid = threadIdx.x;

    // --- weight swizzle (first 55296 global threads) ---
    {
        int t = blockIdx.x * 256 + tid;
        if (t < WBM_ELEMS) {
            int j = t & 7, lane = (t >> 3) & 63, nt = (t >> 9) & 3, kb = t >> 11;
            int k = kb * 32 + ((lane >> 4) << 3) + j;
            int n = nt * 16 + (lane & 15);
            int tap = k >> 6, c = k & 63;
            ws[t] = f2bf(wgt[n * 576 + c * 9 + tap]);
        } else if (t < WBM_ELEMS + WBO_ELEMS) {
            int t2 = t - WBM_ELEMS;
            int j = t2 & 7, lane = (t2 >> 3) & 63, nt = (t2 >> 9) & 1, kb = t2 >> 10;
            int k = kb * 32 + ((lane >> 4) << 3) + j;
            int n = nt * 16 + (lane & 15);
            int tap = k >> 6, c = k & 63;
            ws[t] = (n < 27) ? f2bf(w_off[n * 576 + c * 9 + tap]) : (unsigned short)0;
        }
    }

    // --- transpose ---
    const int bb  = blockIdx.x >> 8;
    const int hw0 = (blockIdx.x & 255) << 6;
    const float* xb = x + ((size_t)bb << 20);
#pragma unroll
    for (int it = 0; it < 16; ++it) {
        int idx = it * 256 + tid;
        int c = idx >> 6, i = idx & 63;
        tile[c * 65 + i] = xb[(c << 14) + hw0 + i];   // coalesced in i
    }
    __syncthreads();
    unsigned int* xtb = (unsigned int*)(ws + XT_OFF) + ((size_t)bb << 19);
#pragma unroll
    for (int it = 0; it < 8; ++it) {
        int idx = it * 256 + tid;
        int i = idx >> 5, c2 = idx & 31;
        unsigned int lo = (unsigned int)f2bf(tile[(2 * c2) * 65 + i]);
        unsigned int hi = (unsigned int)f2bf(tile[(2 * c2 + 1) * 65 + i]);
        xtb[(size_t)(hw0 + i) * 32 + c2] = lo | (hi << 16);   // coalesced in c2
    }
}

// ---------------- main kernel: 1 wave / 32 pixels per block ----------------
__global__ __launch_bounds__(64) void DeformConv_14568529068723_kernel(
    const float* __restrict__ b_off,
    const float* __restrict__ bias,
    const float* __restrict__ gamma,
    const float* __restrict__ beta,
    const float* __restrict__ rmean,
    const float* __restrict__ rvar,
    const unsigned short* __restrict__ ws,
    float* __restrict__ out)
{
    // samp: [32 px][KP2] bf16 staging; aliased by offs f32[27][32] (disjoint
    // lifetime) and dT f32[64][33] (epilogue).
    __shared__ __align__(16) unsigned short samp[32 * KP2];  // 12800 B
    __shared__ float eL[4][9][32];       // bilinear pair weights per (tap,px)
    __shared__ int   oL[2][9][32];       // row0/row1 base element offsets
    __shared__ float sbuf[176];          // 0-63 scale, 64-127 bias2, 128-154 b_off

    const int tid  = threadIdx.x;
    const int px16 = tid & 15;           // MFMA m-lane
    const int cg   = tid >> 4;           // MFMA k-quad
    const int c8   = tid & 7;            // staging: channel group (8 ch)
    const int pxq  = tid >> 3;           // staging: px sub-index (8 px/it)

    {
        float sc = gamma[tid] * __frsqrt_rn(rvar[tid] + 1e-5f);
        sbuf[tid] = sc;
        sbuf[64 + tid] = (bias[tid] - rmean[tid]) * sc + beta[tid];
        if (tid < 27) sbuf[128 + tid] = b_off[tid];
    }

    const int p0   = blockIdx.x * 32;
    const int b    = p0 >> 14;
    const int rem0 = p0 & 16383;
    const int h    = rem0 >> 7;
    const int w0   = rem0 & 127;
    const unsigned short* xt = ws + XT_OFF + ((size_t)b << 20);

    const bf16x8* WbM = (const bf16x8*)ws;
    const bf16x8* WbO = (const bf16x8*)(ws + WBM_ELEMS);

    __syncthreads();

    // ================= offset conv via MFMA (3 chunks of 3 taps, 2 M-tiles) =================
    f32x4 accO[2][2];
#pragma unroll
    for (int mt = 0; mt < 2; ++mt)
#pragma unroll
        for (int q = 0; q < 2; ++q) accO[mt][q] = (f32x4){0.f, 0.f, 0.f, 0.f};

    for (int chk = 0; chk < 3; ++chk) {
#pragma unroll
        for (int tl = 0; tl < 3; ++tl) {
            int tap = chk * 3 + tl;
            int ky = tap / 3 - 1, kx = tap % 3 - 1;
            int yy = h + ky;
            int yc = min(max(yy, 0), HH - 1);
            bool oky = (yy >= 0) & (yy < HH);
#pragma unroll
            for (int it = 0; it < 4; ++it) {
                int px = it * 8 + pxq;
                int xx = w0 + px + kx;
                bool ok = oky & (xx >= 0) & (xx < WW);
                int pos = yc * WW + min(max(xx, 0), WW - 1);
                uint4 v = *(const uint4*)(xt + pos * 64 + (c8 << 3));
                if (!ok) { v.x = 0u; v.y = 0u; v.z = 0u; v.w = 0u; }
                *(uint4*)&samp[px * KP2 + tl * 64 + (c8 << 3)] = v;
            }
        }
        __syncthreads();
#pragma unroll
        for (int st = 0; st < 6; ++st) {
            int kb = chk * 6 + st;
            bf16x8 b0 = WbO[(kb * 2 + 0) * 64 + tid];
            bf16x8 b1 = WbO[(kb * 2 + 1) * 64 + tid];
#pragma unroll
            for (int mt = 0; mt < 2; ++mt) {
                bf16x8 af = *(const bf16x8*)&samp[(mt * 16 + px16) * KP2 + st * 32 + (cg << 3)];
                accO[mt][0] = __builtin_amdgcn_mfma_f32_16x16x32_bf16(af, b0, accO[mt][0], 0, 0, 0);
                accO[mt][1] = __builtin_amdgcn_mfma_f32_16x16x32_bf16(af, b1, accO[mt][1], 0, 0, 0);
            }
        }
        __syncthreads();
    }
    // D -> offs[oc][px32] (aliased into samp), + bias, sigmoid masks.
    float* offs = (float*)samp;          // f32[27][32] = 3456 B
    {
        int n0 = tid & 15;
        int mB = cg * 4;
#pragma unroll
        for (int mt = 0; mt < 2; ++mt)
#pragma unroll
            for (int r = 0; r < 4; ++r) {
                int pxc = mt * 16 + mB + r;
                offs[n0 * 32 + pxc] = accO[mt][0][r] + sbuf[128 + n0];   // oc 0..15
                int n1 = 16 + n0;
                if (n1 < 27) {
                    float vv = accO[mt][1][r] + sbuf[128 + n1];
                    if (n1 >= 18) vv = 1.0f / (1.0f + __expf(-vv));
                    offs[n1 * 32 + pxc] = vv;
                }
            }
    }
    __syncthreads();

    // ========= bilinear setup per (px,tap) -> LDS (corner-select folded into e-weights) =========
#pragma unroll
    for (int base = 0; base < 288; base += 64) {
        int idx = base + tid;
        if (idx < 288) {
            int px = idx & 31, tap = idx >> 5;
            float o1 = offs[(2 * tap) * 32 + px];
            float o2 = offs[(2 * tap + 1) * 32 + px];
            float m  = offs[(18 + tap) * 32 + px];
            float py  = (float)(h + tap / 3 - 1) + o1;
            float pxf = (float)(w0 + px + tap % 3 - 1) + o2;
            float y0f = floorf(py), x0f = floorf(pxf);
            float dy = py - y0f, dx = pxf - x0f;
            int y0 = (int)y0f, x0 = (int)x0f;
            int y1 = y0 + 1, x1 = x0 + 1;
            int yc0 = min(max(y0, 0), HH - 1), yc1 = min(max(y1, 0), HH - 1);
            int xc0 = min(max(x0, 0), WW - 1), xc1 = min(max(x1, 0), WW - 1);
            float vy0 = (y0 >= 0 && y0 < HH) ? 1.0f : 0.0f;
            float vy1 = (y1 >= 0 && y1 < HH) ? 1.0f : 0.0f;
            float vx0 = (x0 >= 0 && x0 < WW) ? 1.0f : 0.0f;
            float vx1 = (x1 >= 0 && x1 < WW) ? 1.0f : 0.0f;
            float c00 = (1.0f - dy) * (1.0f - dx) * m * vy0 * vx0;
            float c01 = (1.0f - dy) * dx * m * vy0 * vx1;
            float c10 = dy * (1.0f - dx) * m * vy1 * vx0;
            float c11 = dy * dx * m * vy1 * vx1;
            int bx = min(xc0, WW - 2);        // column pair [bx, bx+1] in-bounds
            bool s0 = (xc0 != bx), s1 = (xc1 != bx);
            eL[0][tap][px] = (s0 ? 0.f : c00) + (s1 ? 0.f : c01);
            eL[1][tap][px] = (s0 ? c00 : 0.f) + (s1 ? c01 : 0.f);
            eL[2][tap][px] = (s0 ? 0.f : c10) + (s1 ? 0.f : c11);
            eL[3][tap][px] = (s0 ? c10 : 0.f) + (s1 ? c11 : 0.f);
            oL[0][tap][px] = (yc0 * WW + bx) * 64;
            oL[1][tap][px] = (yc1 * WW + bx) * 64;
        }
    }
    __syncthreads();

    // ================= main conv via MFMA (3 chunks of 3 taps, 2 M-tiles) =================
    f32x4 acc[2][4];
#pragma unroll
    for (int mt = 0; mt < 2; ++mt)
#pragma unroll
        for (int nt = 0; nt < 4; ++nt) acc[mt][nt] = (f32x4){0.f, 0.f, 0.f, 0.f};

    for (int chk = 0; chk < 3; ++chk) {
#pragma unroll
        for (int tl = 0; tl < 3; ++tl) {
            int tap = chk * 3 + tl;
#pragma unroll
            for (int it = 0; it < 4; ++it) {
                int px = it * 8 + pxq;
                int o0 = oL[0][tap][px], o1r = oL[1][tap][px];
                float e0 = eL[0][tap][px], e1 = eL[1][tap][px];
                float e2 = eL[2][tap][px], e3 = eL[3][tap][px];
                uint4 a0 = *(const uint4*)(xt + o0 + (c8 << 3));
                uint4 a1 = *(const uint4*)(xt + o0 + 64 + (c8 << 3));
                uint4 b0 = *(const uint4*)(xt + o1r + (c8 << 3));
                uint4 b1 = *(const uint4*)(xt + o1r + 64 + (c8 << 3));
                const unsigned int* pa0 = (const unsigned int*)&a0;
                const unsigned int* pa1 = (const unsigned int*)&a1;
                const unsigned int* pb0 = (const unsigned int*)&b0;
                const unsigned int* pb1 = (const unsigned int*)&b1;
                uint4 pk;
                unsigned int* pp = (unsigned int*)&pk;
#pragma unroll
                for (int q = 0; q < 4; ++q) {
                    float lo = e0 * bf2f((unsigned short)(pa0[q] & 0xffff))
                             + e1 * bf2f((unsigned short)(pa1[q] & 0xffff))
                             + e2 * bf2f((unsigned short)(pb0[q] & 0xffff))
                             + e3 * bf2f((unsigned short)(pb1[q] & 0xffff));
                    float hi = e0 * bf2f((unsigned short)(pa0[q] >> 16))
                             + e1 * bf2f((unsigned short)(pa1[q] >> 16))
                             + e2 * bf2f((unsigned short)(pb0[q] >> 16))
                             + e3 * bf2f((unsigned short)(pb1[q] >> 16));
                    pp[q] = (unsigned int)f2bf(lo) | ((unsigned int)f2bf(hi) << 16);
                }
                *(uint4*)&samp[px * KP2 + tl * 64 + (c8 << 3)] = pk;
            }
        }
        __syncthreads();
#pragma unroll
        for (int st = 0; st < 6; ++st) {
            int kb = chk * 6 + st;
#pragma unroll
            for (int nt = 0; nt < 4; ++nt) {
                bf16x8 bf = WbM[(kb * 4 + nt) * 64 + tid];
#pragma unroll
                for (int mt = 0; mt < 2; ++mt) {
                    bf16x8 af = *(const bf16x8*)&samp[(mt * 16 + px16) * KP2 + st * 32 + (cg << 3)];
                    acc[mt][nt] = __builtin_amdgcn_mfma_f32_16x16x32_bf16(af, bf, acc[mt][nt], 0, 0, 0);
                }
            }
        }
        __syncthreads();
    }

    // ================= epilogue: transpose via LDS, BN + ReLU, coalesced stores ==========
    float* dT = (float*)samp;   // [64 o][33]; 8448 B <= 12800 B
    {
        int n0 = tid & 15;
        int mB = cg * 4;
#pragma unroll
        for (int mt = 0; mt < 2; ++mt)
#pragma unroll
            for (int nt = 0; nt < 4; ++nt)
#pragma unroll
                for (int r = 0; r < 4; ++r)
                    dT[(nt * 16 + n0) * 33 + mt * 16 + mB + r] = acc[mt][nt][r];
    }
    __syncthreads();
    {
        int px = tid & 31;
        int oh = tid >> 5;
#pragma unroll
        for (int i = 0; i < 32; ++i) {
            int o = 2 * i + oh;
            float v = dT[o * 33 + px];
            v = fmaxf(fmaf(v, sbuf[o], sbuf[64 + o]), 0.0f);
            out[(((size_t)(b * 64 + o)) << 14) + rem0 + px] = v;
        }
    }
}

extern "C" void kernel_launch(void* const* d_in, const int* in_sizes, int n_in,
                              void* d_out, int out_size, void* d_ws, size_t ws_size,
                              hipStream_t stream) {
    (void)in_sizes; (void)n_in; (void)ws_size; (void)out_size;
    const float* x     = (const float*)d_in[0];
    const float* w_off = (const float*)d_in[1];
    const float* b_off = (const float*)d_in[2];
    const float* wgt   = (const float*)d_in[3];
    const float* bias  = (const float*)d_in[4];
    const float* gamma = (const float*)d_in[5];
    const float* beta  = (const float*)d_in[6];
    const float* rmean = (const float*)d_in[7];
    const float* rvar  = (const float*)d_in[8];
    unsigned short* wsB = (unsigned short*)d_ws;
    float* outp = (float*)d_out;

    transpose_kernel<<<dim3(1024), dim3(256), 0, stream>>>(x, w_off, wgt, wsB);
    // 65536 px / 32 per block = 2048 blocks of 64 threads (1 wave each)
    DeformConv_14568529068723_kernel<<<dim3(2048), dim3(64), 0, stream>>>(
        b_off, bias, gamma, beta, rmean, rvar, wsB, outp);
}